// Round 1
// baseline (834.253 us; speedup 1.0000x reference)
//
#include <hip/hip_runtime.h>
#include <hip/hip_bf16.h>

#define NROWS 2048
#define DIM   1024
#define VOCAB 32000
#define BM 64
#define BN 128
#define BK 64
#define NRB (NROWS / BM)   // 32
#define NVB (VOCAB / BN)   // 250
#define KSTEPS (DIM / BK)  // 16

typedef __attribute__((ext_vector_type(4))) float f32x4;
typedef __attribute__((ext_vector_type(8))) short bf16x8;

static __device__ inline unsigned short f2bf(float x) {
  union { float f; unsigned u; } c; c.f = x;
  unsigned r = c.u + 0x7fffu + ((c.u >> 16) & 1u);
  return (unsigned short)(r >> 16);
}

// ---------------- Kernel A: target logits (fp32, one wave per row) ---------
__global__ __launch_bounds__(256) void tgt_kernel(
    const float* __restrict__ cell, const float* __restrict__ clsw,
    const int* __restrict__ labels, float* __restrict__ tlog) {
  int wv = threadIdx.x >> 6, lane = threadIdx.x & 63;
  int row = blockIdx.x * 4 + wv;
  int lbl = labels[row];
  const float4* a = (const float4*)(cell + (size_t)row * DIM);
  const float4* b = (const float4*)(clsw + (size_t)lbl * DIM);
  float acc = 0.f;
#pragma unroll
  for (int q = 0; q < 4; ++q) {
    float4 av = a[q * 64 + lane];
    float4 bv = b[q * 64 + lane];
    acc += av.x * bv.x + av.y * bv.y + av.z * bv.z + av.w * bv.w;
  }
#pragma unroll
  for (int off = 32; off >= 1; off >>= 1) acc += __shfl_xor(acc, off);
  if (lane == 0) tlog[row] = acc;
}

// ---------------- Kernel B: bf16 MFMA GEMM + fused partial logsumexp -------
// LDS is "fragment-linear": frag slot (rt, ks) holds 64 lanes x 16B, so the
// MFMA fragment read is one lane-consecutive ds_read_b128 (conflict-free).
// Element (row, k) -> slot = rt*(BK/32)+ks, lane l = (row&15)|(((k>>3)&3)<<4),
// ushort j = k&7.
__global__ __launch_bounds__(256) void gemm_lse_kernel(
    const float* __restrict__ cell, const float* __restrict__ clsw,
    float* __restrict__ partials) {
  __shared__ unsigned short smem[BM * BK + BN * BK];  // 24576 B
  unsigned short* As = smem;
  unsigned short* Bs = smem + BM * BK;

  int bx = blockIdx.x;
  int rb = bx & (NRB - 1);   // fast-varying: 32 consecutive blocks share B tile
  int vb = bx >> 5;
  int tid = threadIdx.x;
  int wv = tid >> 6, lane = tid & 63;

  const float* Abase = cell + (size_t)rb * BM * DIM;
  const float* Bbase = clsw + (size_t)vb * BN * DIM;

  f32x4 acc[8];
#pragma unroll
  for (int i = 0; i < 8; ++i) acc[i] = (f32x4){0.f, 0.f, 0.f, 0.f};

  for (int kt = 0; kt < KSTEPS; ++kt) {
    // ---- stage A tile: 64 rows x 64 k, 1024 float4-slots / 256 threads ----
#pragma unroll
    for (int i = 0; i < (BM * 16) / 256; ++i) {
      int s = tid + 256 * i;
      int row = s >> 4;
      int k0 = (s & 15) * 4;
      float4 v = *(const float4*)(Abase + (size_t)row * DIM + kt * BK + k0);
      int l = (row & 15) | (((k0 >> 3) & 3) << 4);
      int slot = (row >> 4) * 2 + (k0 >> 5);
      ushort4 h = {f2bf(v.x), f2bf(v.y), f2bf(v.z), f2bf(v.w)};
      *(ushort4*)(As + (slot * 64 + l) * 8 + (k0 & 7)) = h;
    }
    // ---- stage B tile: 128 rows(vocab cols) x 64 k ----
#pragma unroll
    for (int i = 0; i < (BN * 16) / 256; ++i) {
      int s = tid + 256 * i;
      int row = s >> 4;
      int k0 = (s & 15) * 4;
      float4 v = *(const float4*)(Bbase + (size_t)row * DIM + kt * BK + k0);
      int l = (row & 15) | (((k0 >> 3) & 3) << 4);
      int slot = (row >> 4) * 2 + (k0 >> 5);
      ushort4 h = {f2bf(v.x), f2bf(v.y), f2bf(v.z), f2bf(v.w)};
      *(ushort4*)(Bs + (slot * 64 + l) * 8 + (k0 & 7)) = h;
    }
    __syncthreads();

    bf16x8 a0 = *(const bf16x8*)(As + ((wv * 2 + 0) * 64 + lane) * 8);
    bf16x8 a1 = *(const bf16x8*)(As + ((wv * 2 + 1) * 64 + lane) * 8);
#pragma unroll
    for (int ct = 0; ct < 8; ++ct) {
      bf16x8 b0 = *(const bf16x8*)(Bs + ((ct * 2 + 0) * 64 + lane) * 8);
      bf16x8 b1 = *(const bf16x8*)(Bs + ((ct * 2 + 1) * 64 + lane) * 8);
      acc[ct] = __builtin_amdgcn_mfma_f32_16x16x32_bf16(a0, b0, acc[ct], 0, 0, 0);
      acc[ct] = __builtin_amdgcn_mfma_f32_16x16x32_bf16(a1, b1, acc[ct], 0, 0, 0);
    }
    __syncthreads();
  }

  // ---- fused epilogue: per-row (max, sum-exp) over this BN=128 col tile ----
  // C layout (m89): col = lane&15, row = (lane>>4)*4 + reg.
#pragma unroll
  for (int i = 0; i < 4; ++i) {
    float m = acc[0][i];
#pragma unroll
    for (int ct = 1; ct < 8; ++ct) m = fmaxf(m, acc[ct][i]);
    float s = 0.f;
#pragma unroll
    for (int ct = 0; ct < 8; ++ct) s += __expf(acc[ct][i] - m);
#pragma unroll
    for (int off = 1; off <= 8; off <<= 1) {  // combine across 16 cols-lanes
      float om = __shfl_xor(m, off);
      float os = __shfl_xor(s, off);
      float nm = fmaxf(m, om);
      s = s * __expf(m - nm) + os * __expf(om - nm);
      m = nm;
    }
    if ((lane & 15) == 0) {
      int grow = rb * BM + wv * 16 + (lane >> 4) * 4 + i;
      float2 o = make_float2(m, s);
      *(float2*)(partials + ((size_t)grow * NVB + vb) * 2) = o;
    }
  }
}

// ---------------- Kernel C: per-row combine + mean NLL ---------------------
__global__ __launch_bounds__(256) void reduce_kernel(
    const float* __restrict__ partials, const float* __restrict__ tlog,
    float* __restrict__ out) {
  int wv = threadIdx.x >> 6, lane = threadIdx.x & 63;
  int row = blockIdx.x * 4 + wv;
  const float2* p = (const float2*)(partials + (size_t)row * NVB * 2);
  float m = -1e30f, s = 0.f;
  for (int i = lane; i < NVB; i += 64) {
    float2 v = p[i];
    float nm = fmaxf(m, v.x);
    s = s * __expf(m - nm) + v.y * __expf(v.x - nm);
    m = nm;
  }
#pragma unroll
  for (int off = 1; off <= 32; off <<= 1) {
    float om = __shfl_xor(m, off);
    float os = __shfl_xor(s, off);
    float nm = fmaxf(m, om);
    s = s * __expf(m - nm) + os * __expf(om - nm);
    m = nm;
  }
  float loss = m + __logf(s) - tlog[row];
  __shared__ float red[4];
  if (lane == 0) red[wv] = loss;
  __syncthreads();
  if (threadIdx.x == 0)
    atomicAdd(out, (red[0] + red[1] + red[2] + red[3]) * (1.0f / NROWS));
}

extern "C" void kernel_launch(void* const* d_in, const int* in_sizes, int n_in,
                              void* d_out, int out_size, void* d_ws, size_t ws_size,
                              hipStream_t stream) {
  const float* cell = (const float*)d_in[0];
  const float* clsw = (const float*)d_in[1];
  const int* labels = (const int*)d_in[2];
  float* out = (float*)d_out;
  float* tlog = (float*)d_ws;                           // 2048 f32
  float* partials = (float*)((char*)d_ws + 8192);       // [2048][250][2] f32

  hipMemsetAsync(d_out, 0, sizeof(float), stream);
  tgt_kernel<<<NROWS / 4, 256, 0, stream>>>(cell, clsw, labels, tlog);
  gemm_lse_kernel<<<NRB * NVB, 256, 0, stream>>>(cell, clsw, partials);
  reduce_kernel<<<NROWS / 4, 256, 0, stream>>>(partials, tlog, out);
}

// Round 4
// 488.575 us; speedup vs baseline: 1.7075x; 1.7075x over previous
//
#include <hip/hip_runtime.h>

#define NROWS 2048
#define DIM   1024
#define VOCAB 32000
#define BM 128
#define BN 128
#define BK 64
#define NRB (NROWS / BM)    // 16
#define NVB (VOCAB / BN)    // 250
#define NCB (NVB * 2)       // 500 col-blocks of 64
#define KSTEPS (DIM / BK)   // 16

typedef __attribute__((ext_vector_type(4))) float f32x4;
typedef __attribute__((ext_vector_type(8))) short bf16x8;
typedef unsigned int u32;

static __device__ inline unsigned short f2bf(float x) {
  union { float f; unsigned u; } c; c.f = x;
  unsigned r = c.u + 0x7fffu + ((c.u >> 16) & 1u);
  return (unsigned short)(r >> 16);
}

// ---------------- fp32 -> bf16 pre-convert (8 elems/thread) ----------------
__global__ __launch_bounds__(256) void cvt_kernel(const float* __restrict__ in,
                                                  unsigned short* __restrict__ out) {
  int i = blockIdx.x * 256 + threadIdx.x;
  const float4* p = (const float4*)in;
  float4 v0 = p[i * 2], v1 = p[i * 2 + 1];
  ushort4 h0 = {f2bf(v0.x), f2bf(v0.y), f2bf(v0.z), f2bf(v0.w)};
  ushort4 h1 = {f2bf(v1.x), f2bf(v1.y), f2bf(v1.z), f2bf(v1.w)};
  ((ushort4*)out)[i * 2] = h0;
  ((ushort4*)out)[i * 2 + 1] = h1;
}

// ---------------- target logits (fp32, one wave per row) -------------------
__global__ __launch_bounds__(256) void tgt_kernel(
    const float* __restrict__ cell, const float* __restrict__ clsw,
    const int* __restrict__ labels, float* __restrict__ tlog) {
  int wv = threadIdx.x >> 6, lane = threadIdx.x & 63;
  int row = blockIdx.x * 4 + wv;
  int lbl = labels[row];
  const float4* a = (const float4*)(cell + (size_t)row * DIM);
  const float4* b = (const float4*)(clsw + (size_t)lbl * DIM);
  float acc = 0.f;
#pragma unroll
  for (int q = 0; q < 4; ++q) {
    float4 av = a[q * 64 + lane];
    float4 bv = b[q * 64 + lane];
    acc += av.x * bv.x + av.y * bv.y + av.z * bv.z + av.w * bv.w;
  }
#pragma unroll
  for (int off = 32; off >= 1; off >>= 1) acc += __shfl_xor(acc, off);
  if (lane == 0) tlog[row] = acc;
}

// ---------------- bf16 MFMA GEMM + fused partial logsumexp -----------------
// Fragment-linear LDS: slot t (t = rt*2+ks, rt = 16-row tile, ks = 32-k tile)
// holds 64 lanes x 16B at byte offset t*1024. global_load_lds dest is linear
// (wave base + lane*16); the per-lane GLOBAL address is pre-swizzled so lane l
// fetches row rt*16+(l&15), k = ks*32+(l>>4)*8 — exactly the mfma bf16 A/B
// fragment. ds_read_b128 of a fragment is then one contiguous 1024B wave read
// (conflict-free), and LDS writes are the canonical conflict-free pattern.
__global__ __launch_bounds__(256) void gemm_lse_kernel(
    const unsigned short* __restrict__ Ab, const unsigned short* __restrict__ Bb,
    float* __restrict__ partials) {
  __shared__ unsigned short smem[2 * BM * BK];  // A 16KB + B 16KB
  unsigned short* As = smem;
  unsigned short* Bs = smem + BM * BK;

  const int bx = blockIdx.x;
  const int rb = bx & (NRB - 1);   // fast: 16 consecutive blocks share B panel
  const int vb = bx >> 4;
  const int tid = threadIdx.x;
  const int wv = tid >> 6, lane = tid & 63;
  const int wr = wv >> 1, wc = wv & 1;

  const size_t Abase = (size_t)rb * BM * DIM;
  const size_t Bbase = (size_t)vb * BN * DIM;

  // per-lane swizzled source offset pieces (slot t = wv*4+q)
  const int lrow = lane & 15;
  const int lk = (lane >> 4) * 8;

  f32x4 acc[4][4];
#pragma unroll
  for (int m = 0; m < 4; ++m)
#pragma unroll
    for (int n = 0; n < 4; ++n) acc[m][n] = (f32x4){0.f, 0.f, 0.f, 0.f};

  for (int kt = 0; kt < KSTEPS; ++kt) {
#pragma unroll
    for (int q = 0; q < 4; ++q) {
      const int t = wv * 4 + q;          // slot 0..15
      const int rt = t >> 1, ks = t & 1;
      const int row = rt * 16 + lrow;
      const int k = kt * BK + ks * 32 + lk;
      __builtin_amdgcn_global_load_lds(
          (const __attribute__((address_space(1))) u32*)(Ab + Abase + (size_t)row * DIM + k),
          (__attribute__((address_space(3))) u32*)(As + t * 512), 16, 0, 0);
      __builtin_amdgcn_global_load_lds(
          (const __attribute__((address_space(1))) u32*)(Bb + Bbase + (size_t)row * DIM + k),
          (__attribute__((address_space(3))) u32*)(Bs + t * 512), 16, 0, 0);
    }
    __syncthreads();
#pragma unroll
    for (int ks = 0; ks < 2; ++ks) {
      bf16x8 a[4], b[4];
#pragma unroll
      for (int m = 0; m < 4; ++m)
        a[m] = *(const bf16x8*)(As + ((wr * 4 + m) * 2 + ks) * 512 + lane * 8);
#pragma unroll
      for (int n = 0; n < 4; ++n)
        b[n] = *(const bf16x8*)(Bs + ((wc * 4 + n) * 2 + ks) * 512 + lane * 8);
#pragma unroll
      for (int m = 0; m < 4; ++m)
#pragma unroll
        for (int n = 0; n < 4; ++n)
          acc[m][n] = __builtin_amdgcn_mfma_f32_16x16x32_bf16(a[m], b[n], acc[m][n], 0, 0, 0);
    }
    __syncthreads();
  }

  // fused epilogue: per-row (max, sum-exp) over this wave's 64-col slab.
  // C layout (m89): col = lane&15, row = (lane>>4)*4 + i.
#pragma unroll
  for (int m = 0; m < 4; ++m) {
#pragma unroll
    for (int i = 0; i < 4; ++i) {
      float mx = acc[m][0][i];
#pragma unroll
      for (int n = 1; n < 4; ++n) mx = fmaxf(mx, acc[m][n][i]);
      float s = 0.f;
#pragma unroll
      for (int n = 0; n < 4; ++n) s += __expf(acc[m][n][i] - mx);
#pragma unroll
      for (int off = 1; off <= 8; off <<= 1) {  // combine 16 col-lanes
        float om = __shfl_xor(mx, off);
        float os = __shfl_xor(s, off);
        float nm = fmaxf(mx, om);
        s = s * __expf(mx - nm) + os * __expf(om - nm);
        mx = nm;
      }
      if ((lane & 15) == 0) {
        int grow = rb * BM + wr * 64 + m * 16 + (lane >> 4) * 4 + i;
        int cb = vb * 2 + wc;
        *(float2*)(partials + ((size_t)grow * NCB + cb) * 2) = make_float2(mx, s);
      }
    }
  }
}

// ---------------- per-row combine + mean NLL -------------------------------
__global__ __launch_bounds__(256) void reduce_kernel(
    const float* __restrict__ partials, const float* __restrict__ tlog,
    float* __restrict__ out) {
  int wv = threadIdx.x >> 6, lane = threadIdx.x & 63;
  int row = blockIdx.x * 4 + wv;
  const float2* p = (const float2*)(partials + (size_t)row * NCB * 2);
  float m = -1e30f, s = 0.f;
  for (int i = lane; i < NCB; i += 64) {
    float2 v = p[i];
    float nm = fmaxf(m, v.x);
    s = s * __expf(m - nm) + v.y * __expf(v.x - nm);
    m = nm;
  }
#pragma unroll
  for (int off = 1; off <= 32; off <<= 1) {
    float om = __shfl_xor(m, off);
    float os = __shfl_xor(s, off);
    float nm = fmaxf(m, om);
    s = s * __expf(m - nm) + os * __expf(om - nm);
    m = nm;
  }
  float loss = m + __logf(s) - tlog[row];
  __shared__ float red[4];
  if (lane == 0) red[wv] = loss;
  __syncthreads();
  if (threadIdx.x == 0)
    atomicAdd(out, (red[0] + red[1] + red[2] + red[3]) * (1.0f / NROWS));
}

extern "C" void kernel_launch(void* const* d_in, const int* in_sizes, int n_in,
                              void* d_out, int out_size, void* d_ws, size_t ws_size,
                              hipStream_t stream) {
  const float* cell = (const float*)d_in[0];
  const float* clsw = (const float*)d_in[1];
  const int* labels = (const int*)d_in[2];
  float* out = (float*)d_out;

  unsigned short* cellb = (unsigned short*)d_ws;                       // 4 MB
  unsigned short* clswb = (unsigned short*)((char*)d_ws + 4194304);    // 65.5 MB
  float* tlog = (float*)((char*)d_ws + 69730304);                      // 8 KB
  float* partials = (float*)((char*)d_ws + 69738496);                  // 8.2 MB

  hipMemsetAsync(out, 0, sizeof(float), stream);
  cvt_kernel<<<(NROWS * DIM) / (256 * 8), 256, 0, stream>>>(cell, cellb);
  cvt_kernel<<<(VOCAB * DIM) / (256 * 8), 256, 0, stream>>>(clsw, clswb);
  tgt_kernel<<<NROWS / 4, 256, 0, stream>>>(cell, clsw, labels, tlog);
  gemm_lse_kernel<<<NRB * NVB, 256, 0, stream>>>(cellb, clswb, partials);
  reduce_kernel<<<NROWS / 4, 256, 0, stream>>>(partials, tlog, out);
}

// Round 6
// 404.125 us; speedup vs baseline: 2.0643x; 1.2090x over previous
//
#include <hip/hip_runtime.h>

#define NROWS 2048
#define DIM   1024
#define VOCAB 32000
#define BM 256
#define BN 256
#define BK 64
#define NRB (NROWS / BM)    // 8
#define NVB (VOCAB / BN)    // 125
#define NCB (VOCAB / 64)    // 500 col-blocks of 64
#define KSTEPS (DIM / BK)   // 16

typedef __attribute__((ext_vector_type(4))) float f32x4;
typedef __attribute__((ext_vector_type(8))) short bf16x8;
typedef unsigned int u32;

static __device__ inline unsigned short f2bf(float x) {
  union { float f; unsigned u; } c; c.f = x;
  unsigned r = c.u + 0x7fffu + ((c.u >> 16) & 1u);
  return (unsigned short)(r >> 16);
}

// ---------------- fp32 -> bf16 pre-convert, fully coalesced ----------------
__global__ __launch_bounds__(256) void cvt_kernel(const float* __restrict__ in,
                                                  unsigned short* __restrict__ out) {
  int base = blockIdx.x * 512 + threadIdx.x;
  const float4* p = (const float4*)in;
  ushort4* o = (ushort4*)out;
  float4 v0 = p[base];
  float4 v1 = p[base + 256];
  ushort4 h0 = {f2bf(v0.x), f2bf(v0.y), f2bf(v0.z), f2bf(v0.w)};
  ushort4 h1 = {f2bf(v1.x), f2bf(v1.y), f2bf(v1.z), f2bf(v1.w)};
  o[base] = h0;
  o[base + 256] = h1;
}

// ---------------- target logits (fp32, one wave per row) -------------------
__global__ __launch_bounds__(256) void tgt_kernel(
    const float* __restrict__ cell, const float* __restrict__ clsw,
    const int* __restrict__ labels, float* __restrict__ tlog) {
  int wv = threadIdx.x >> 6, lane = threadIdx.x & 63;
  int row = blockIdx.x * 4 + wv;
  int lbl = labels[row];
  const float4* a = (const float4*)(cell + (size_t)row * DIM);
  const float4* b = (const float4*)(clsw + (size_t)lbl * DIM);
  float acc = 0.f;
#pragma unroll
  for (int q = 0; q < 4; ++q) {
    float4 av = a[q * 64 + lane];
    float4 bv = b[q * 64 + lane];
    acc += av.x * bv.x + av.y * bv.y + av.z * bv.z + av.w * bv.w;
  }
#pragma unroll
  for (int off = 32; off >= 1; off >>= 1) acc += __shfl_xor(acc, off);
  if (lane == 0) tlog[row] = acc;
}

// ---------------- bf16 MFMA 256x256 GEMM + fused partial logsumexp ---------
// Fragment-linear LDS (conflict-free by construction): slot t = rt*2+ks holds
// 64 lanes x 16B at byte offset t*1024 of the A/B region. global_load_lds dest
// is linear (wave base + lane*16); per-lane GLOBAL address pre-swizzled so
// lane l fetches row rt*16+(l&15), k = ks*32+(l>>4)*8 — the mfma bf16
// fragment. Double-buffered, counted vmcnt(8): each wave stages 8 slots/tile,
// so vmcnt(8) = "previous tile's stores landed, next tile's still in flight".
// Raw s_barrier (NOT __syncthreads) keeps the prefetch queue alive across the
// barrier (the m97 ~20% drain).
__global__ __launch_bounds__(512) void gemm_lse_kernel(
    const unsigned short* __restrict__ Ab, const unsigned short* __restrict__ Bb,
    float* __restrict__ partials) {
  __shared__ unsigned short smem[65536];  // 128 KB: 2 bufs x (A 32KB | B 32KB)

  const int h = blockIdx.x;
  // XCD chunk swizzle (bijective: 1000 % 8 == 0): blocks sharing a B panel
  // land on the same XCD's L2.
  const int g = (h & 7) * (NRB * NVB / 8) + (h >> 3);
  const int rb = g & (NRB - 1);
  const int vb = g >> 3;
  const int tid = threadIdx.x;
  const int wv = tid >> 6, lane = tid & 63;
  const int wr = wv >> 2, wc = wv & 3;    // 2x4 wave grid; wave owns 128x64
  const int lrow = lane & 15;
  const int lk = (lane >> 4) * 8;

  const size_t Abase = (size_t)rb * BM * DIM;
  const size_t Bbase = (size_t)vb * BN * DIM;

  f32x4 acc[8][4];
#pragma unroll
  for (int m = 0; m < 8; ++m)
#pragma unroll
    for (int n = 0; n < 4; ++n) acc[m][n] = (f32x4){0.f, 0.f, 0.f, 0.f};

  auto STAGE = [&](int kt, int buf) {
    unsigned short* As_ = smem + buf * 32768;
    unsigned short* Bs_ = As_ + 16384;
    const int kb = kt * BK;
#pragma unroll
    for (int q = 0; q < 4; ++q) {
      const int t = wv * 4 + q;          // slot 0..31
      const int rt = t >> 1, ks = t & 1;
      const size_t off = (size_t)(rt * 16 + lrow) * DIM + kb + ks * 32 + lk;
      __builtin_amdgcn_global_load_lds(
          (const __attribute__((address_space(1))) u32*)(Ab + Abase + off),
          (__attribute__((address_space(3))) u32*)(As_ + t * 512), 16, 0, 0);
      __builtin_amdgcn_global_load_lds(
          (const __attribute__((address_space(1))) u32*)(Bb + Bbase + off),
          (__attribute__((address_space(3))) u32*)(Bs_ + t * 512), 16, 0, 0);
    }
  };

  auto COMPUTE = [&](int buf) {
    const unsigned short* As_ = smem + buf * 32768;
    const unsigned short* Bs_ = As_ + 16384;
    __builtin_amdgcn_s_setprio(1);
#pragma unroll
    for (int ks = 0; ks < 2; ++ks) {
      bf16x8 b[4];
#pragma unroll
      for (int n = 0; n < 4; ++n)
        b[n] = *(const bf16x8*)(Bs_ + ((wc * 4 + n) * 2 + ks) * 512 + lane * 8);
#pragma unroll
      for (int m = 0; m < 8; ++m) {
        bf16x8 a = *(const bf16x8*)(As_ + ((wr * 8 + m) * 2 + ks) * 512 + lane * 8);
#pragma unroll
        for (int n = 0; n < 4; ++n)
          acc[m][n] = __builtin_amdgcn_mfma_f32_16x16x32_bf16(a, b[n], acc[m][n], 0, 0, 0);
      }
    }
    __builtin_amdgcn_s_setprio(0);
  };

  STAGE(0, 0);
  for (int kt = 0; kt < KSTEPS - 1; ++kt) {
    const int cur = kt & 1;
    STAGE(kt + 1, cur ^ 1);                          // prefetch next tile
    asm volatile("s_waitcnt vmcnt(8)" ::: "memory"); // cur tile landed
    __builtin_amdgcn_sched_barrier(0);
    __builtin_amdgcn_s_barrier();
    __builtin_amdgcn_sched_barrier(0);
    COMPUTE(cur);
    asm volatile("s_waitcnt lgkmcnt(0)" ::: "memory"); // my ds_reads drained
    __builtin_amdgcn_sched_barrier(0);
    __builtin_amdgcn_s_barrier();                     // buf[cur] now reusable
    __builtin_amdgcn_sched_barrier(0);
  }
  asm volatile("s_waitcnt vmcnt(0)" ::: "memory");
  __builtin_amdgcn_sched_barrier(0);
  __builtin_amdgcn_s_barrier();
  __builtin_amdgcn_sched_barrier(0);
  COMPUTE((KSTEPS - 1) & 1);

  // fused epilogue: per-row (max, sum-exp) over this wave's 64-col slab.
  // C layout (m89): col = lane&15, row = (lane>>4)*4 + i.
#pragma unroll
  for (int m = 0; m < 8; ++m) {
#pragma unroll
    for (int i = 0; i < 4; ++i) {
      float mx = acc[m][0][i];
#pragma unroll
      for (int n = 1; n < 4; ++n) mx = fmaxf(mx, acc[m][n][i]);
      float s = 0.f;
#pragma unroll
      for (int n = 0; n < 4; ++n) s += __expf(acc[m][n][i] - mx);
#pragma unroll
      for (int off = 1; off <= 8; off <<= 1) {  // combine 16 col-lanes
        float om = __shfl_xor(mx, off);
        float os = __shfl_xor(s, off);
        float nm = fmaxf(mx, om);
        s = s * __expf(mx - nm) + os * __expf(om - nm);
        mx = nm;
      }
      if ((lane & 15) == 0) {
        int grow = rb * BM + wr * 128 + m * 16 + (lane >> 4) * 4 + i;
        int cb = vb * 4 + wc;
        *(float2*)(partials + ((size_t)grow * NCB + cb) * 2) = make_float2(mx, s);
      }
    }
  }
}

// ---------------- per-row combine + mean NLL -------------------------------
__global__ __launch_bounds__(256) void reduce_kernel(
    const float* __restrict__ partials, const float* __restrict__ tlog,
    float* __restrict__ out) {
  int wv = threadIdx.x >> 6, lane = threadIdx.x & 63;
  int row = blockIdx.x * 4 + wv;
  const float2* p = (const float2*)(partials + (size_t)row * NCB * 2);
  float m = -1e30f, s = 0.f;
  for (int i = lane; i < NCB; i += 64) {
    float2 v = p[i];
    float nm = fmaxf(m, v.x);
    s = s * __expf(m - nm) + v.y * __expf(v.x - nm);
    m = nm;
  }
#pragma unroll
  for (int off = 1; off <= 32; off <<= 1) {
    float om = __shfl_xor(m, off);
    float os = __shfl_xor(s, off);
    float nm = fmaxf(m, om);
    s = s * __expf(m - nm) + os * __expf(om - nm);
    m = nm;
  }
  float loss = m + __logf(s) - tlog[row];
  __shared__ float red[4];
  if (lane == 0) red[wv] = loss;
  __syncthreads();
  if (threadIdx.x == 0)
    atomicAdd(out, (red[0] + red[1] + red[2] + red[3]) * (1.0f / NROWS));
}

extern "C" void kernel_launch(void* const* d_in, const int* in_sizes, int n_in,
                              void* d_out, int out_size, void* d_ws, size_t ws_size,
                              hipStream_t stream) {
  const float* cell = (const float*)d_in[0];
  const float* clsw = (const float*)d_in[1];
  const int* labels = (const int*)d_in[2];
  float* out = (float*)d_out;

  unsigned short* cellb = (unsigned short*)d_ws;                       // 4 MB
  unsigned short* clswb = (unsigned short*)((char*)d_ws + 4194304);    // 65.5 MB
  float* tlog = (float*)((char*)d_ws + 69730304);                      // 8 KB
  float* partials = (float*)((char*)d_ws + 69738496);                  // 8.2 MB

  hipMemsetAsync(out, 0, sizeof(float), stream);
  cvt_kernel<<<(NROWS * DIM / 4) / 512, 256, 0, stream>>>(cell, cellb);
  cvt_kernel<<<(VOCAB * DIM / 4) / 512, 256, 0, stream>>>(clsw, clswb);
  tgt_kernel<<<NROWS / 4, 256, 0, stream>>>(cell, clsw, labels, tlog);
  gemm_lse_kernel<<<NRB * NVB, 512, 0, stream>>>(cellb, clswb, partials);
  reduce_kernel<<<NROWS / 4, 256, 0, stream>>>(partials, tlog, out);
}